// Round 16
// baseline (926.783 us; speedup 1.0000x reference)
//
#include <hip/hip_runtime.h>
#include <hip/hip_bf16.h>

typedef unsigned short u16;
typedef __bf16 bf16x8 __attribute__((ext_vector_type(8)));
typedef float f32x4 __attribute__((ext_vector_type(4)));

#define HH 56
#define WW 56
#define DIM 384
#define NTOK 100352   // 32*3136
#define NWIN 2048     // 32*64
#define NN 49

__device__ __forceinline__ u16 f2bf(float f) {
    __hip_bfloat16 h = __float2bfloat16(f);
    return *reinterpret_cast<u16*>(&h);
}
__device__ __forceinline__ float bf2f(u16 u) {
    union { unsigned int i; float f; } c; c.i = ((unsigned int)u) << 16; return c.f;
}

// exact-GELU: gelu(x) = 0.5*x*(1+erf(x/sqrt2)), erf via A&S 7.1.26 (max err 1.5e-7)
__device__ __forceinline__ float fast_gelu(float x) {
    float au = fabsf(x) * 0.70710678118654752f;
    float t = __builtin_amdgcn_rcpf(fmaf(0.3275911f, au, 1.0f));
    float p = fmaf(t, 1.061405429f, -1.453152027f);
    p = fmaf(t, p, 1.421413741f);
    p = fmaf(t, p, -0.284496736f);
    p = fmaf(t, p, 0.254829592f);
    p = p * t;
    float e = __expf(-au * au);
    float erfau = fmaf(-p, e, 1.0f);
    float erfx = __builtin_copysignf(erfau, x);
    return 0.5f * x * (1.0f + erfx);
}

#define GLD_LDS(gp, lp) __builtin_amdgcn_global_load_lds( \
    (const __attribute__((address_space(1))) void*)(gp), \
    (__attribute__((address_space(3))) void*)(lp), 16, 0, 0)

// ---------------- weight transpose + cast: in (K,N) f32 -> out (N,K) bf16 ----
__global__ void castT(const float* __restrict__ in, u16* __restrict__ out, int K, int N) {
    int i = blockIdx.x * 256 + threadIdx.x;
    if (i < N * K) {
        int n = i / K, kk = i - n * K;
        out[i] = f2bf(in[(size_t)kk * N + n]);
    }
}

// ---------------- bias table: Tb[ty][head][q][kk] = rel_bias + mask (+pad) ---
__global__ void bias_kernel(const float* __restrict__ rel_bias, float* __restrict__ Tb) {
    int ty = blockIdx.x / 12, h = blockIdx.x - ty * 12;
    for (int i = threadIdx.x; i < 4096; i += 256) {
        int q = i >> 6, kk = i & 63;
        float v;
        if (kk >= 49) v = -1e30f;
        else if (q >= 49) v = 0.f;
        else {
            int rn = q / 7, cn = q - rn * 7;
            int rm = kk / 7, cm = kk - rm * 7;
            float rb = rel_bias[((rn - rm + 6) * 13 + (cn - cm + 6)) * 12 + h];
            int h0 = (ty >> 1) ? 49 : 0;
            int w0 = (ty & 1) ? 49 : 0;
            int hn = h0 + rn, hm = h0 + rm, wn = w0 + cn, wm = w0 + cm;
            int regn = (hn < 49 ? 0 : (hn < 53 ? 1 : 2)) * 3 + (wn < 49 ? 0 : (wn < 53 ? 1 : 2));
            int regm = (hm < 49 ? 0 : (hm < 53 ? 1 : 2)) * 3 + (wm < 49 ? 0 : (wm < 53 ? 1 : 2));
            v = rb + ((regn == regm) ? 0.f : -10000.f);
        }
        Tb[(size_t)blockIdx.x * 4096 + i] = v;
    }
}

// ---------------- LayerNorm (one wave per token). WIN_MAP: write to windowed pos
template<bool WIN_MAP>
__global__ __launch_bounds__(256) void ln_kernel(
    const float* __restrict__ x, const float* __restrict__ w, const float* __restrict__ b,
    u16* __restrict__ out)
{
    int token = blockIdx.x * 4 + (threadIdx.x >> 6);
    int lane = threadIdx.x & 63;
    const float* row = x + (size_t)token * DIM;
    float v[6]; float sum = 0.f, sq = 0.f;
#pragma unroll
    for (int j = 0; j < 3; j++) {
        float2 p = *(const float2*)(row + lane * 2 + j * 128);
        v[2*j] = p.x; v[2*j+1] = p.y;
        sum += p.x + p.y; sq += p.x * p.x + p.y * p.y;
    }
#pragma unroll
    for (int off = 32; off; off >>= 1) { sum += __shfl_xor(sum, off); sq += __shfl_xor(sq, off); }
    float mu = sum * (1.f / DIM);
    float rstd = rsqrtf(sq * (1.f / DIM) - mu * mu + 1e-5f);
    size_t obase;
    if (WIN_MAP) {
        int b_ = token / 3136, hw = token - b_ * 3136;
        int h = hw / WW, wc_ = hw - h * WW;
        int hr = h - 3; if (hr < 0) hr += HH;
        int wr = wc_ - 3; if (wr < 0) wr += WW;
        int win = b_ * 64 + (hr / 7) * 8 + (wr / 7);
        int n = (hr % 7) * 7 + (wr % 7);
        obase = ((size_t)win * NN + n) * DIM;
    } else {
        obase = (size_t)token * DIM;
    }
#pragma unroll
    for (int j = 0; j < 3; j++) {
        int c = lane * 2 + j * 128;
        float a0 = (v[2*j]   - mu) * rstd * w[c]   + b[c];
        float a1 = (v[2*j+1] - mu) * rstd * w[c+1] + b[c+1];
        unsigned int pair = (unsigned int)f2bf(a0) | ((unsigned int)f2bf(a1) << 16);
        *(unsigned int*)(out + obase + c) = pair;
    }
}

// ---------------- GEMM: C = A(MxK) * Bt(NxK)^T + bias, bf16 in, fp32 acc -----
// 256x128 tile, 8 waves, 2-buffer / 2-barrier counted schedule (48 KB LDS).
// PERSISTENT MULTI-TILE (TPB tiles / physical block) with cross-tile prefetch:
// tile j's last two K-steps stage tile j+1's first two K-tiles -> the staging
// stream never breaks; fill bubble paid once per TPB tiles. Uniform vmcnt(3).
// Block p owns XCD-chunk p&7, within-chunk positions (p>>3)*TPB + j (preserves
// bn-inner locality + REV/LIFO chaining). TPB=1 degenerates to r15 exactly.
template<int EPI, bool REV, int TPB>
__global__ __launch_bounds__(512, 4) void gemm_kernel(
    const u16* __restrict__ A, const u16* __restrict__ Bt,
    const float* __restrict__ bias, const float* __restrict__ resid,
    void* __restrict__ outp, int N, int K, int BNT, int NT_TOT)
{
    __shared__ u16 sA[2][8192];   // 256 x 32
    __shared__ u16 sB[2][4096];   // 128 x 32
    const int tid = threadIdx.x;
    const int lane = tid & 63;
    const int wave = tid >> 6;
    const int wr = wave >> 1, wc = wave & 1;   // 4 x 2 wave grid

    const int q8t = NT_TOT >> 3;
    const int chunk = blockIdx.x & 7;
    const int base = (blockIdx.x >> 3) * TPB;

    const int r0 = tid >> 2;
    const int sg = (tid & 3) ^ (r0 & 3) ^ ((r0 >> 2) & 3);
    const int nt = K >> 5;
    const int l15 = lane & 15, g = lane >> 4;
    const int ssr = (g ^ (l15 & 3) ^ ((l15 >> 2) & 3)) * 8;

#define DECODE(j, oA0, oA1, oB0, obm, obn) do { \
        int wg_ = chunk * q8t + base + (j); \
        if (REV) wg_ = NT_TOT - 1 - wg_; \
        obm = wg_ / BNT; obn = wg_ - obm * BNT; \
        oA0 = A + (size_t)(obm * 256 + r0) * K + sg * 8; \
        oA1 = oA0 + (size_t)128 * K; \
        oB0 = Bt + (size_t)(obn * 128 + r0) * K + sg * 8; \
    } while (0)

#define STAGEP(t, buf, pA0, pA1, pB0) do { \
        int kt_ = (t) * 32; \
        GLD_LDS(pA0 + kt_, &sA[buf][wave * 512]); \
        GLD_LDS(pA1 + kt_, &sA[buf][4096 + wave * 512]); \
        GLD_LDS(pB0 + kt_, &sB[buf][wave * 512]); \
    } while (0)

    const u16 *cA0, *cA1, *cB0;
    int cbm, cbn;
    DECODE(0, cA0, cA1, cB0, cbm, cbn);
    const u16 *nA0 = cA0, *nA1 = cA1, *nB0 = cB0;
    int nbm = cbm, nbn = cbn;

    STAGEP(0, 0, cA0, cA1, cB0);
    STAGEP(1, 1, cA0, cA1, cB0);

    for (int j = 0; j < TPB; j++) {
        const bool hasNext = (j + 1 < TPB);
        if (hasNext) DECODE(j + 1, nA0, nA1, nB0, nbm, nbn);
        f32x4 acc[4][4] = {};
        for (int t = 0; t < nt; t++) {
            const int bsel = t & 1;
            // own tile-step landed (later loads may still be in flight)
            if (t + 1 < nt || hasNext) asm volatile("s_waitcnt vmcnt(3)" ::: "memory");
            else                       asm volatile("s_waitcnt vmcnt(0)" ::: "memory");
            __builtin_amdgcn_s_barrier();            // publish step t
            __builtin_amdgcn_sched_barrier(0);
            bf16x8 af[4], bfr[4];
#pragma unroll
            for (int m = 0; m < 4; m++) {
                int row = wr * 64 + m * 16 + l15;
                af[m] = *(const bf16x8*)&sA[bsel][row * 32 + ssr];
            }
#pragma unroll
            for (int n = 0; n < 4; n++) {
                int row = wc * 64 + n * 16 + l15;
                bfr[n] = *(const bf16x8*)&sB[bsel][row * 32 + ssr];
            }
            asm volatile("s_waitcnt lgkmcnt(0)" ::: "memory");  // step t in regs
            __builtin_amdgcn_sched_barrier(0);
            __builtin_amdgcn_s_barrier();            // all waves done reading
            __builtin_amdgcn_sched_barrier(0);
            if (t + 2 < nt)   STAGEP(t + 2, bsel, cA0, cA1, cB0);
            else if (hasNext) STAGEP(t + 2 - nt, bsel, nA0, nA1, nB0);  // cross-tile prefetch
#pragma unroll
            for (int m = 0; m < 4; m++)
#pragma unroll
                for (int n = 0; n < 4; n++)
                    acc[m][n] = __builtin_amdgcn_mfma_f32_16x16x32_bf16(af[m], bfr[n], acc[m][n], 0, 0, 0);
        }

        // ---- epilogue for tile j (r12 unswapped layout) ----
        const int col0 = cbn * 128 + wc * 64 + l15;
        float bias4[4];
#pragma unroll
        for (int nn = 0; nn < 4; nn++) bias4[nn] = bias[col0 + nn * 16];

#pragma unroll
        for (int m = 0; m < 4; m++) {
#pragma unroll
            for (int r = 0; r < 4; r++) {
                int row = cbm * 256 + wr * 64 + m * 16 + (g << 2) + r;
                size_t obase;
                if (EPI == 1) {
                    int win = row / NN, n = row - win * NN;
                    int b_ = win >> 6, wi = win & 63;
                    int hr = (wi >> 3) * 7 + n / 7;
                    int wcl = (wi & 7) * 7 + n % 7;
                    int hf = hr + 3; if (hf >= HH) hf -= HH;
                    int wf = wcl + 3; if (wf >= WW) wf -= WW;
                    obase = ((size_t)b_ * 3136 + hf * WW + wf) * DIM;
                } else {
                    obase = (size_t)row * N;
                }
#pragma unroll
                for (int nn = 0; nn < 4; nn++) {
                    int col = col0 + nn * 16;
                    float val = acc[m][nn][r] + bias4[nn];
                    if (EPI == 0) {
                        ((u16*)outp)[obase + col] = f2bf(val);
                    } else if (EPI == 1) {
                        ((float*)outp)[obase + col] = val + resid[obase + col];
                    } else if (EPI == 2) {
                        ((u16*)outp)[obase + col] = f2bf(fast_gelu(val));
                    } else {
                        ((float*)outp)[obase + col] = val + resid[obase + col];
                    }
                }
            }
        }
        cA0 = nA0; cA1 = nA1; cB0 = nB0; cbm = nbm; cbn = nbn;
    }
#undef STAGEP
#undef DECODE
}

// ---------------- MFMA windowed attention: one wave per (window, head) -------
__global__ __launch_bounds__(256) void attn_kernel(
    const u16* __restrict__ qkv, const float* __restrict__ Tb,
    u16* __restrict__ attn_out)
{
    // per-wave LDS: Vt[32][72] + P[64][72] (u16), 13824 B/wave
    __shared__ u16 smem[4][6912];
    const int win = blockIdx.x;
    const int wave = threadIdx.x >> 6;
    const int lane = threadIdx.x & 63;
    const int head = blockIdx.y * 4 + wave;
    const int l15 = lane & 15, g = lane >> 4;

    u16* Vt = smem[wave];
    u16* P  = Vt + 2304;

    const u16* qkvw = qkv + (size_t)win * NN * 1152 + head * 32;

    // ---- stage V transposed (zero-pad rows >= 49) ----
    {
        int m = lane;
        bool real = m < NN;
        const u16* vrow = qkvw + (size_t)(real ? m : 0) * 1152 + 768;
        int4 z = {0,0,0,0};
        int4 c0 = real ? *(const int4*)(vrow)      : z;
        int4 c1 = real ? *(const int4*)(vrow + 8)  : z;
        int4 c2 = real ? *(const int4*)(vrow + 16) : z;
        int4 c3 = real ? *(const int4*)(vrow + 24) : z;
        u16 vals[32];
        *(int4*)&vals[0]  = c0; *(int4*)&vals[8]  = c1;
        *(int4*)&vals[16] = c2; *(int4*)&vals[24] = c3;
#pragma unroll
        for (int d = 0; d < 32; d++) Vt[d * 72 + m] = vals[d];
    }

    // ---- S^T = K * Q^T via MFMA (rows clamped to 48: no garbage) ----
    bf16x8 kf[4], qf[4];
#pragma unroll
    for (int t = 0; t < 4; t++) {
        int row = t * 16 + l15; if (row > 48) row = 48;
        const u16* base = qkvw + (size_t)row * 1152 + g * 8;
        kf[t] = *(const bf16x8*)(base + 384);
        qf[t] = *(const bf16x8*)(base);
    }
    f32x4 s[4][4];   // [key-tile mt][query-tile nt]
#pragma unroll
    for (int mt = 0; mt < 4; mt++)
#pragma unroll
        for (int nt = 0; nt < 4; nt++) {
            f32x4 zero = {};
            s[mt][nt] = __builtin_amdgcn_mfma_f32_16x16x32_bf16(kf[mt], qf[nt], zero, 0, 0, 0);
        }

    // ---- bias + mask + softmax (query = nt*16 + l15, keys in regs) ----
    const int wi = win & 63;
    const int ty = (((wi >> 3) == 7) ? 2 : 0) + (((wi & 7) == 7) ? 1 : 0);
    const float* tbb = Tb + (((size_t)ty * 12 + head) << 12);
    const float SCALE = 0.17677669529663687f;
#pragma unroll
    for (int nt = 0; nt < 4; nt++) {
        int q = nt * 16 + l15;
        const float* trow = tbb + q * 64 + g * 4;
        f32x4 b[4];
#pragma unroll
        for (int mt = 0; mt < 4; mt++) b[mt] = *(const f32x4*)(trow + mt * 16);
        float mx = -3e38f;
#pragma unroll
        for (int mt = 0; mt < 4; mt++)
#pragma unroll
            for (int r = 0; r < 4; r++) {
                float v = s[mt][nt][r] * SCALE + b[mt][r];
                s[mt][nt][r] = v;
                mx = fmaxf(mx, v);
            }
        mx = fmaxf(mx, __shfl_xor(mx, 16));
        mx = fmaxf(mx, __shfl_xor(mx, 32));
        float sum = 0.f;
#pragma unroll
        for (int mt = 0; mt < 4; mt++)
#pragma unroll
            for (int r = 0; r < 4; r++) {
                float e = __expf(s[mt][nt][r] - mx);
                s[mt][nt][r] = e;
                sum += e;
            }
        sum += __shfl_xor(sum, 16);
        sum += __shfl_xor(sum, 32);
        float inv = 1.f / sum;
#pragma unroll
        for (int mt = 0; mt < 4; mt++) {
            unsigned int p01 = (unsigned int)f2bf(s[mt][nt][0] * inv) | ((unsigned int)f2bf(s[mt][nt][1] * inv) << 16);
            unsigned int p23 = (unsigned int)f2bf(s[mt][nt][2] * inv) | ((unsigned int)f2bf(s[mt][nt][3] * inv) << 16);
            uint2 pk; pk.x = p01; pk.y = p23;
            *(uint2*)&P[(unsigned)q * 72 + mt * 16 + g * 4] = pk;
        }
    }

    // ---- O = P * V via MFMA ----
    bf16x8 vf[2][2];
#pragma unroll
    for (int ks = 0; ks < 2; ks++)
#pragma unroll
        for (int dt = 0; dt < 2; dt++)
            vf[ks][dt] = *(const bf16x8*)&Vt[(dt * 16 + l15) * 72 + ks * 32 + g * 8];

    f32x4 o[4][2] = {};
#pragma unroll
    for (int nt = 0; nt < 4; nt++) {
        bf16x8 pf0 = *(const bf16x8*)&P[(nt * 16 + l15) * 72 + g * 8];
        bf16x8 pf1 = *(const bf16x8*)&P[(nt * 16 + l15) * 72 + 32 + g * 8];
#pragma unroll
        for (int dt = 0; dt < 2; dt++) {
            o[nt][dt] = __builtin_amdgcn_mfma_f32_16x16x32_bf16(pf0, vf[0][dt], o[nt][dt], 0, 0, 0);
            o[nt][dt] = __builtin_amdgcn_mfma_f32_16x16x32_bf16(pf1, vf[1][dt], o[nt][dt], 0, 0, 0);
        }
    }

    // ---- write out ----
#pragma unroll
    for (int nt = 0; nt < 4; nt++)
#pragma unroll
        for (int r = 0; r < 4; r++) {
            int q = nt * 16 + 4 * g + r;
            if (q < NN) {
                size_t ob = ((size_t)win * NN + q) * DIM + head * 32;
                attn_out[ob + l15]      = f2bf(o[nt][0][r]);
                attn_out[ob + 16 + l15] = f2bf(o[nt][1][r]);
            }
        }
}

// ---------------- launch ------------------------------------------------------
extern "C" void kernel_launch(void* const* d_in, const int* in_sizes, int n_in,
                              void* d_out, int out_size, void* d_ws, size_t ws_size,
                              hipStream_t stream)
{
    const float* x      = (const float*)d_in[0];
    const float* qkv_w  = (const float*)d_in[1];
    const float* qkv_b  = (const float*)d_in[2];
    const float* proj_w = (const float*)d_in[3];
    const float* proj_b = (const float*)d_in[4];
    const float* rel_b  = (const float*)d_in[5];
    const float* n1w    = (const float*)d_in[6];
    const float* n1b    = (const float*)d_in[7];
    const float* n2w    = (const float*)d_in[8];
    const float* n2b    = (const float*)d_in[9];
    const float* w1     = (const float*)d_in[10];
    const float* b1     = (const float*)d_in[11];
    const float* w2     = (const float*)d_in[12];
    const float* b2     = (const float*)d_in[13];

    char* ws = (char*)d_ws;
    u16* hidden  = (u16*)(ws);                       // 100352x1536 bf16 (MLP hidden)
    u16* qkvbuf  = hidden;                           // 100352x1152 bf16 (aliases hidden)
    float* Tb    = (float*)(ws + 231211008);         // 4x12x64x64 f32 bias table
    u16* wxbuf   = (u16*)(ws + 308281344);           // 100352x384 bf16 (wx / attn_out / ln2)
    u16* qkv_wt  = (u16*)(ws + 385351680);           // 1152x384
    u16* proj_wt = (u16*)(ws + 386236416);           // 384x384
    u16* w1t     = (u16*)(ws + 386531328);           // 1536x384
    u16* w2t     = (u16*)(ws + 387710976);           // 384x1536

    castT<<<(1152*384 + 255) / 256, 256, 0, stream>>>(qkv_w, qkv_wt, 384, 1152);
    castT<<<(384*384  + 255) / 256, 256, 0, stream>>>(proj_w, proj_wt, 384, 384);
    castT<<<(384*1536 + 255) / 256, 256, 0, stream>>>(w1, w1t, 384, 1536);
    castT<<<(1536*384 + 255) / 256, 256, 0, stream>>>(w2, w2t, 1536, 384);
    bias_kernel<<<48, 256, 0, stream>>>(rel_b, Tb);

    // LN1 + roll + window partition (fwd write order)
    ln_kernel<true><<<NTOK / 4, 256, 0, stream>>>(x, n1w, n1b, wxbuf);
    // QKV GEMM — persistent TPB=3 (1176 blocks), REV/LIFO
    gemm_kernel<0, true, 3><<<1176, 512, 0, stream>>>(wxbuf, qkv_wt, qkv_b, nullptr, qkvbuf, 1152, 384, 9, 3528);
    // attention (fwd)
    attn_kernel<<<dim3(NWIN, 3), 256, 0, stream>>>(qkvbuf, Tb, wxbuf);
    // proj GEMM + window reverse + roll + residual -> y1 (TPB=1, REV)
    gemm_kernel<1, true, 1><<<1176, 512, 0, stream>>>(wxbuf, proj_wt, proj_b, x, d_out, 384, 384, 3, 1176);
    // LN2 on y1 -> wxbuf (fwd)
    ln_kernel<false><<<NTOK / 4, 256, 0, stream>>>((const float*)d_out, n2w, n2b, wxbuf);
    // MLP1 + GELU -> hidden — persistent TPB=6 (784 blocks), REV
    gemm_kernel<2, true, 6><<<784, 512, 0, stream>>>(wxbuf, w1t, b1, nullptr, hidden, 1536, 384, 12, 4704);
    // MLP2 + residual(y1) -> d_out (TPB=1, fwd)
    gemm_kernel<3, false, 1><<<1176, 512, 0, stream>>>(hidden, w2t, b2, (const float*)d_out, d_out, 384, 1536, 3, 1176);
}

// Round 17
// 862.729 us; speedup vs baseline: 1.0742x; 1.0742x over previous
//
#include <hip/hip_runtime.h>
#include <hip/hip_bf16.h>

typedef unsigned short u16;
typedef __bf16 bf16x8 __attribute__((ext_vector_type(8)));
typedef float f32x4 __attribute__((ext_vector_type(4)));

#define HH 56
#define WW 56
#define DIM 384
#define NTOK 100352   // 32*3136
#define NWIN 2048     // 32*64
#define NN 49

__device__ __forceinline__ u16 f2bf(float f) {
    __hip_bfloat16 h = __float2bfloat16(f);
    return *reinterpret_cast<u16*>(&h);
}
__device__ __forceinline__ float bf2f(u16 u) {
    union { unsigned int i; float f; } c; c.i = ((unsigned int)u) << 16; return c.f;
}

// exact-GELU: gelu(x) = 0.5*x*(1+erf(x/sqrt2)), erf via A&S 7.1.26 (max err 1.5e-7)
__device__ __forceinline__ float fast_gelu(float x) {
    float au = fabsf(x) * 0.70710678118654752f;
    float t = __builtin_amdgcn_rcpf(fmaf(0.3275911f, au, 1.0f));
    float p = fmaf(t, 1.061405429f, -1.453152027f);
    p = fmaf(t, p, 1.421413741f);
    p = fmaf(t, p, -0.284496736f);
    p = fmaf(t, p, 0.254829592f);
    p = p * t;
    float e = __expf(-au * au);
    float erfau = fmaf(-p, e, 1.0f);
    float erfx = __builtin_copysignf(erfau, x);
    return 0.5f * x * (1.0f + erfx);
}

#define GLD_LDS(gp, lp) __builtin_amdgcn_global_load_lds( \
    (const __attribute__((address_space(1))) void*)(gp), \
    (__attribute__((address_space(3))) void*)(lp), 16, 0, 0)

// ---------------- fused weight transpose+cast: 4 matrices, 32x32 LDS tiles ---
// in (K,N) f32 -> out (N,K) bf16, coalesced both sides (r16 fix: the old
// per-element castT read fully strided -> ~16x fetch inflation).
__global__ __launch_bounds__(256) void castT_all(
    const float* __restrict__ qkv_w, const float* __restrict__ proj_w,
    const float* __restrict__ w1, const float* __restrict__ w2,
    u16* __restrict__ qkv_wt, u16* __restrict__ proj_wt,
    u16* __restrict__ w1t, u16* __restrict__ w2t)
{
    int b = blockIdx.x;
    const float* in; u16* out; int K, N, tile;
    if (b < 432)       { in = qkv_w;  out = qkv_wt;  K = 384;  N = 1152; tile = b; }
    else if (b < 576)  { in = proj_w; out = proj_wt; K = 384;  N = 384;  tile = b - 432; }
    else if (b < 1152) { in = w1;     out = w1t;     K = 384;  N = 1536; tile = b - 576; }
    else               { in = w2;     out = w2t;     K = 1536; N = 384;  tile = b - 1152; }
    const int ncols = N >> 5;
    const int tn = tile % ncols, tk = tile / ncols;
    const int n0 = tn * 32, k0 = tk * 32;
    __shared__ float ts[32][33];
    const int tr = threadIdx.x >> 3;
    const int tc = (threadIdx.x & 7) * 4;
    const float4 v = *(const float4*)(in + (size_t)(k0 + tr) * N + n0 + tc);
    ts[tr][tc] = v.x; ts[tr][tc+1] = v.y; ts[tr][tc+2] = v.z; ts[tr][tc+3] = v.w;
    __syncthreads();
    u16 o4[4];
    o4[0] = f2bf(ts[tc][tr]);     o4[1] = f2bf(ts[tc+1][tr]);
    o4[2] = f2bf(ts[tc+2][tr]);   o4[3] = f2bf(ts[tc+3][tr]);
    *(uint2*)(out + (size_t)(n0 + tr) * K + k0 + tc) = *(uint2*)o4;
}

// ---------------- bias table: Tb[ty][head][q][kk] = rel_bias + mask (+pad) ---
__global__ void bias_kernel(const float* __restrict__ rel_bias, float* __restrict__ Tb) {
    int ty = blockIdx.x / 12, h = blockIdx.x - ty * 12;
    for (int i = threadIdx.x; i < 4096; i += 256) {
        int q = i >> 6, kk = i & 63;
        float v;
        if (kk >= 49) v = -1e30f;
        else if (q >= 49) v = 0.f;
        else {
            int rn = q / 7, cn = q - rn * 7;
            int rm = kk / 7, cm = kk - rm * 7;
            float rb = rel_bias[((rn - rm + 6) * 13 + (cn - cm + 6)) * 12 + h];
            int h0 = (ty >> 1) ? 49 : 0;
            int w0 = (ty & 1) ? 49 : 0;
            int hn = h0 + rn, hm = h0 + rm, wn = w0 + cn, wm = w0 + cm;
            int regn = (hn < 49 ? 0 : (hn < 53 ? 1 : 2)) * 3 + (wn < 49 ? 0 : (wn < 53 ? 1 : 2));
            int regm = (hm < 49 ? 0 : (hm < 53 ? 1 : 2)) * 3 + (wm < 49 ? 0 : (wm < 53 ? 1 : 2));
            v = rb + ((regn == regm) ? 0.f : -10000.f);
        }
        Tb[(size_t)blockIdx.x * 4096 + i] = v;
    }
}

// ---------------- LayerNorm (one wave per token). WIN_MAP: write to windowed pos
template<bool WIN_MAP>
__global__ __launch_bounds__(256) void ln_kernel(
    const float* __restrict__ x, const float* __restrict__ w, const float* __restrict__ b,
    u16* __restrict__ out)
{
    int token = blockIdx.x * 4 + (threadIdx.x >> 6);
    int lane = threadIdx.x & 63;
    const float* row = x + (size_t)token * DIM;
    float v[6]; float sum = 0.f, sq = 0.f;
#pragma unroll
    for (int j = 0; j < 3; j++) {
        float2 p = *(const float2*)(row + lane * 2 + j * 128);
        v[2*j] = p.x; v[2*j+1] = p.y;
        sum += p.x + p.y; sq += p.x * p.x + p.y * p.y;
    }
#pragma unroll
    for (int off = 32; off; off >>= 1) { sum += __shfl_xor(sum, off); sq += __shfl_xor(sq, off); }
    float mu = sum * (1.f / DIM);
    float rstd = rsqrtf(sq * (1.f / DIM) - mu * mu + 1e-5f);
    size_t obase;
    if (WIN_MAP) {
        int b_ = token / 3136, hw = token - b_ * 3136;
        int h = hw / WW, wc_ = hw - h * WW;
        int hr = h - 3; if (hr < 0) hr += HH;
        int wr = wc_ - 3; if (wr < 0) wr += WW;
        int win = b_ * 64 + (hr / 7) * 8 + (wr / 7);
        int n = (hr % 7) * 7 + (wr % 7);
        obase = ((size_t)win * NN + n) * DIM;
    } else {
        obase = (size_t)token * DIM;
    }
#pragma unroll
    for (int j = 0; j < 3; j++) {
        int c = lane * 2 + j * 128;
        float a0 = (v[2*j]   - mu) * rstd * w[c]   + b[c];
        float a1 = (v[2*j+1] - mu) * rstd * w[c+1] + b[c+1];
        unsigned int pair = (unsigned int)f2bf(a0) | ((unsigned int)f2bf(a1) << 16);
        *(unsigned int*)(out + obase + c) = pair;
    }
}

// ---------------- GEMM: C = A(MxK) * Bt(NxK)^T + bias, bf16 in, fp32 acc -----
// r15 structure (session best): 256x128 tile, 8 waves, 2-buffer / 2-barrier
// counted schedule (48 KB LDS), __launch_bounds__(512,4), slot-XOR swizzle,
// XCD-bijective swizzle, REV/LIFO chaining, unswapped epilogue.
template<int EPI, bool REV>
__global__ __launch_bounds__(512, 4) void gemm_kernel(
    const u16* __restrict__ A, const u16* __restrict__ Bt,
    const float* __restrict__ bias, const float* __restrict__ resid,
    void* __restrict__ outp, int N, int K, int BNT)
{
    __shared__ u16 sA[2][8192];   // 256 x 32
    __shared__ u16 sB[2][4096];   // 128 x 32
    const int tid = threadIdx.x;
    const int lane = tid & 63;
    const int wave = tid >> 6;
    const int wr = wave >> 1, wc = wave & 1;   // 4 x 2 wave grid

    const int q8 = gridDim.x >> 3;
    int wg = (blockIdx.x & 7) * q8 + (blockIdx.x >> 3);
    if (REV) wg = gridDim.x - 1 - wg;          // per-chunk descending bm (LIFO)
    const int bm = wg / BNT, bn = wg - bm * BNT;

    f32x4 acc[4][4] = {};

    const int r0 = tid >> 2;
    const int sg = (tid & 3) ^ (r0 & 3) ^ ((r0 >> 2) & 3);
    const u16* Arow0 = A + (size_t)(bm * 256 + r0) * K + sg * 8;
    const u16* Arow1 = Arow0 + (size_t)128 * K;
    const u16* Brow0 = Bt + (size_t)(bn * 128 + r0) * K + sg * 8;

    const int nt = K >> 5;

#define STAGE(t, buf) do { \
        int kt_ = (t) * 32; \
        GLD_LDS(Arow0 + kt_, &sA[buf][wave * 512]); \
        GLD_LDS(Arow1 + kt_, &sA[buf][4096 + wave * 512]); \
        GLD_LDS(Brow0 + kt_, &sB[buf][wave * 512]); \
    } while (0)

    STAGE(0, 0); STAGE(1, 1);

    const int l15 = lane & 15, g = lane >> 4;
    const int ssr = (g ^ (l15 & 3) ^ ((l15 >> 2) & 3)) * 8;

    for (int t = 0; t < nt; t++) {
        const int bsel = t & 1;
        // tile t landed (t+1's 3 loads may still be in flight)
        if (t + 1 < nt) asm volatile("s_waitcnt vmcnt(3)" ::: "memory");
        else            asm volatile("s_waitcnt vmcnt(0)" ::: "memory");
        __builtin_amdgcn_s_barrier();            // publish tile t
        __builtin_amdgcn_sched_barrier(0);
        bf16x8 af[4], bfr[4];
#pragma unroll
        for (int m = 0; m < 4; m++) {
            int row = wr * 64 + m * 16 + l15;
            af[m] = *(const bf16x8*)&sA[bsel][row * 32 + ssr];
        }
#pragma unroll
        for (int n = 0; n < 4; n++) {
            int row = wc * 64 + n * 16 + l15;
            bfr[n] = *(const bf16x8*)&sB[bsel][row * 32 + ssr];
        }
        asm volatile("s_waitcnt lgkmcnt(0)" ::: "memory");  // tile t in regs
        __builtin_amdgcn_sched_barrier(0);
        __builtin_amdgcn_s_barrier();            // all waves done reading tile t
        __builtin_amdgcn_sched_barrier(0);
        if (t + 2 < nt) STAGE(t + 2, bsel);      // reuse freed buffer; overlaps MFMA
#pragma unroll
        for (int m = 0; m < 4; m++)
#pragma unroll
            for (int n = 0; n < 4; n++)
                acc[m][n] = __builtin_amdgcn_mfma_f32_16x16x32_bf16(af[m], bfr[n], acc[m][n], 0, 0, 0);
    }
#undef STAGE

    // ---- epilogue (unswapped layout) ----
    const int col0 = bn * 128 + wc * 64 + l15;
    float bias4[4];
#pragma unroll
    for (int nn = 0; nn < 4; nn++) bias4[nn] = bias[col0 + nn * 16];

#pragma unroll
    for (int m = 0; m < 4; m++) {
#pragma unroll
        for (int r = 0; r < 4; r++) {
            int row = bm * 256 + wr * 64 + m * 16 + (g << 2) + r;
            size_t obase;
            if (EPI == 1) {
                int win = row / NN, n = row - win * NN;
                int b_ = win >> 6, wi = win & 63;
                int hr = (wi >> 3) * 7 + n / 7;
                int wcl = (wi & 7) * 7 + n % 7;
                int hf = hr + 3; if (hf >= HH) hf -= HH;
                int wf = wcl + 3; if (wf >= WW) wf -= WW;
                obase = ((size_t)b_ * 3136 + hf * WW + wf) * DIM;
            } else {
                obase = (size_t)row * N;
            }
#pragma unroll
            for (int nn = 0; nn < 4; nn++) {
                int col = col0 + nn * 16;
                float val = acc[m][nn][r] + bias4[nn];
                if (EPI == 0) {
                    ((u16*)outp)[obase + col] = f2bf(val);
                } else if (EPI == 1) {
                    ((float*)outp)[obase + col] = val + resid[obase + col];
                } else if (EPI == 2) {
                    ((u16*)outp)[obase + col] = f2bf(fast_gelu(val));
                } else {
                    ((float*)outp)[obase + col] = val + resid[obase + col];
                }
            }
        }
    }
}

// ---------------- MFMA windowed attention: one wave per (window, head) -------
__global__ __launch_bounds__(256) void attn_kernel(
    const u16* __restrict__ qkv, const float* __restrict__ Tb,
    u16* __restrict__ attn_out)
{
    // per-wave LDS: Vt[32][72] + P[64][72] (u16), 13824 B/wave
    __shared__ u16 smem[4][6912];
    const int win = blockIdx.x;
    const int wave = threadIdx.x >> 6;
    const int lane = threadIdx.x & 63;
    const int head = blockIdx.y * 4 + wave;
    const int l15 = lane & 15, g = lane >> 4;

    u16* Vt = smem[wave];
    u16* P  = Vt + 2304;

    const u16* qkvw = qkv + (size_t)win * NN * 1152 + head * 32;

    // ---- stage V transposed (zero-pad rows >= 49) ----
    {
        int m = lane;
        bool real = m < NN;
        const u16* vrow = qkvw + (size_t)(real ? m : 0) * 1152 + 768;
        int4 z = {0,0,0,0};
        int4 c0 = real ? *(const int4*)(vrow)      : z;
        int4 c1 = real ? *(const int4*)(vrow + 8)  : z;
        int4 c2 = real ? *(const int4*)(vrow + 16) : z;
        int4 c3 = real ? *(const int4*)(vrow + 24) : z;
        u16 vals[32];
        *(int4*)&vals[0]  = c0; *(int4*)&vals[8]  = c1;
        *(int4*)&vals[16] = c2; *(int4*)&vals[24] = c3;
#pragma unroll
        for (int d = 0; d < 32; d++) Vt[d * 72 + m] = vals[d];
    }

    // ---- S^T = K * Q^T via MFMA (rows clamped to 48: no garbage) ----
    bf16x8 kf[4], qf[4];
#pragma unroll
    for (int t = 0; t < 4; t++) {
        int row = t * 16 + l15; if (row > 48) row = 48;
        const u16* base = qkvw + (size_t)row * 1152 + g * 8;
        kf[t] = *(const bf16x8*)(base + 384);
        qf[t] = *(const bf16x8*)(base);
    }
    f32x4 s[4][4];   // [key-tile mt][query-tile nt]
#pragma unroll
    for (int mt = 0; mt < 4; mt++)
#pragma unroll
        for (int nt = 0; nt < 4; nt++) {
            f32x4 zero = {};
            s[mt][nt] = __builtin_amdgcn_mfma_f32_16x16x32_bf16(kf[mt], qf[nt], zero, 0, 0, 0);
        }

    // ---- bias + mask + softmax (query = nt*16 + l15, keys in regs) ----
    const int wi = win & 63;
    const int ty = (((wi >> 3) == 7) ? 2 : 0) + (((wi & 7) == 7) ? 1 : 0);
    const float* tbb = Tb + (((size_t)ty * 12 + head) << 12);
    const float SCALE = 0.17677669529663687f;
#pragma unroll
    for (int nt = 0; nt < 4; nt++) {
        int q = nt * 16 + l15;
        const float* trow = tbb + q * 64 + g * 4;
        f32x4 b[4];
#pragma unroll
        for (int mt = 0; mt < 4; mt++) b[mt] = *(const f32x4*)(trow + mt * 16);
        float mx = -3e38f;
#pragma unroll
        for (int mt = 0; mt < 4; mt++)
#pragma unroll
            for (int r = 0; r < 4; r++) {
                float v = s[mt][nt][r] * SCALE + b[mt][r];
                s[mt][nt][r] = v;
                mx = fmaxf(mx, v);
            }
        mx = fmaxf(mx, __shfl_xor(mx, 16));
        mx = fmaxf(mx, __shfl_xor(mx, 32));
        float sum = 0.f;
#pragma unroll
        for (int mt = 0; mt < 4; mt++)
#pragma unroll
            for (int r = 0; r < 4; r++) {
                float e = __expf(s[mt][nt][r] - mx);
                s[mt][nt][r] = e;
                sum += e;
            }
        sum += __shfl_xor(sum, 16);
        sum += __shfl_xor(sum, 32);
        float inv = 1.f / sum;
#pragma unroll
        for (int mt = 0; mt < 4; mt++) {
            unsigned int p01 = (unsigned int)f2bf(s[mt][nt][0] * inv) | ((unsigned int)f2bf(s[mt][nt][1] * inv) << 16);
            unsigned int p23 = (unsigned int)f2bf(s[mt][nt][2] * inv) | ((unsigned int)f2bf(s[mt][nt][3] * inv) << 16);
            uint2 pk; pk.x = p01; pk.y = p23;
            *(uint2*)&P[(unsigned)q * 72 + mt * 16 + g * 4] = pk;
        }
    }

    // ---- O = P * V via MFMA ----
    bf16x8 vf[2][2];
#pragma unroll
    for (int ks = 0; ks < 2; ks++)
#pragma unroll
        for (int dt = 0; dt < 2; dt++)
            vf[ks][dt] = *(const bf16x8*)&Vt[(dt * 16 + l15) * 72 + ks * 32 + g * 8];

    f32x4 o[4][2] = {};
#pragma unroll
    for (int nt = 0; nt < 4; nt++) {
        bf16x8 pf0 = *(const bf16x8*)&P[(nt * 16 + l15) * 72 + g * 8];
        bf16x8 pf1 = *(const bf16x8*)&P[(nt * 16 + l15) * 72 + 32 + g * 8];
#pragma unroll
        for (int dt = 0; dt < 2; dt++) {
            o[nt][dt] = __builtin_amdgcn_mfma_f32_16x16x32_bf16(pf0, vf[0][dt], o[nt][dt], 0, 0, 0);
            o[nt][dt] = __builtin_amdgcn_mfma_f32_16x16x32_bf16(pf1, vf[1][dt], o[nt][dt], 0, 0, 0);
        }
    }

    // ---- write out ----
#pragma unroll
    for (int nt = 0; nt < 4; nt++)
#pragma unroll
        for (int r = 0; r < 4; r++) {
            int q = nt * 16 + 4 * g + r;
            if (q < NN) {
                size_t ob = ((size_t)win * NN + q) * DIM + head * 32;
                attn_out[ob + l15]      = f2bf(o[nt][0][r]);
                attn_out[ob + 16 + l15] = f2bf(o[nt][1][r]);
            }
        }
}

// ---------------- launch ------------------------------------------------------
extern "C" void kernel_launch(void* const* d_in, const int* in_sizes, int n_in,
                              void* d_out, int out_size, void* d_ws, size_t ws_size,
                              hipStream_t stream)
{
    const float* x      = (const float*)d_in[0];
    const float* qkv_w  = (const float*)d_in[1];
    const float* qkv_b  = (const float*)d_in[2];
    const float* proj_w = (const float*)d_in[3];
    const float* proj_b = (const float*)d_in[4];
    const float* rel_b  = (const float*)d_in[5];
    const float* n1w    = (const float*)d_in[6];
    const float* n1b    = (const float*)d_in[7];
    const float* n2w    = (const float*)d_in[8];
    const float* n2b    = (const float*)d_in[9];
    const float* w1     = (const float*)d_in[10];
    const float* b1     = (const float*)d_in[11];
    const float* w2     = (const float*)d_in[12];
    const float* b2     = (const float*)d_in[13];

    char* ws = (char*)d_ws;
    u16* hidden  = (u16*)(ws);                       // 100352x1536 bf16 (MLP hidden)
    u16* qkvbuf  = hidden;                           // 100352x1152 bf16 (aliases hidden)
    float* Tb    = (float*)(ws + 231211008);         // 4x12x64x64 f32 bias table
    u16* wxbuf   = (u16*)(ws + 308281344);           // 100352x384 bf16 (wx / attn_out / ln2)
    u16* qkv_wt  = (u16*)(ws + 385351680);           // 1152x384
    u16* proj_wt = (u16*)(ws + 386236416);           // 384x384
    u16* w1t     = (u16*)(ws + 386531328);           // 1536x384
    u16* w2t     = (u16*)(ws + 387710976);           // 384x1536

    // fused weight transpose+cast (coalesced 32x32 tiles): 432+144+576+576 blocks
    castT_all<<<1728, 256, 0, stream>>>(qkv_w, proj_w, w1, w2, qkv_wt, proj_wt, w1t, w2t);
    bias_kernel<<<48, 256, 0, stream>>>(rel_b, Tb);

    // LN1 + roll + window partition (fwd write order)
    ln_kernel<true><<<NTOK / 4, 256, 0, stream>>>(x, n1w, n1b, wxbuf);
    // QKV GEMM — REV: writes qkvbuf per-chunk descending; attn (fwd) reads LIFO from L3
    gemm_kernel<0, true><<<392 * 9, 512, 0, stream>>>(wxbuf, qkv_wt, qkv_b, nullptr, qkvbuf, 1152, 384, 9);
    // attention (fwd)
    attn_kernel<<<dim3(NWIN, 3), 256, 0, stream>>>(qkvbuf, Tb, wxbuf);
    // proj GEMM + window reverse + roll + residual -> y1 (REV: ln2 fwd reads LIFO)
    gemm_kernel<1, true><<<392 * 3, 512, 0, stream>>>(wxbuf, proj_wt, proj_b, x, d_out, 384, 384, 3);
    // LN2 on y1 -> wxbuf (fwd)
    ln_kernel<false><<<NTOK / 4, 256, 0, stream>>>((const float*)d_out, n2w, n2b, wxbuf);
    // MLP1 + GELU -> hidden (REV: writes hidden descending; MLP2 fwd reads LIFO)
    gemm_kernel<2, true><<<392 * 12, 512, 0, stream>>>(wxbuf, w1t, b1, nullptr, hidden, 1536, 384, 12);
    // MLP2 + residual(y1) -> d_out (fwd)
    gemm_kernel<3, false><<<392 * 3, 512, 0, stream>>>(hidden, w2t, b2, (const float*)d_out, d_out, 384, 1536, 3);
}